// Round 6
// baseline (168.220 us; speedup 1.0000x reference)
//
#include <hip/hip_runtime.h>
#include <hip/hip_bf16.h>
#include <math.h>

// Problem constants
#define NB 131072
#define NC 128
#define NE 128
__device__ constexpr float S_    = 100.0f;
__device__ constexpr float COSM_ = 0.5403023058681398f;   // cos(1)
__device__ constexpr float SINM_ = 0.8414709848078965f;   // sin(1)
__device__ constexpr float TH_   = -0.5403023058681398f;  // cos(pi-1)
__device__ constexpr float MM_   = 0.8414709848078965f;   // sin(pi-1)*1
__device__ constexpr float C0_   = 25.0f;                 // fixed logsumexp stabilizer

using short8 = __attribute__((ext_vector_type(8))) short;
using f32x4  = __attribute__((ext_vector_type(4))) float;

// fp32 -> bf16 (RNE) on raw bits (kernel 1)
__device__ __forceinline__ unsigned int bf1(float f) {
    unsigned int u = __float_as_uint(f);
    return (u + 0x7FFFu + ((u >> 16) & 1u)) >> 16;
}
// packed fp32x2 -> bf16x2 (v_cvt_pk_bf16_f32)
__device__ __forceinline__ unsigned int pk2(float a, float b) {
    __hip_bfloat162 h = __float22bfloat162_rn(make_float2(a, b));
    union { __hip_bfloat162 h; unsigned int u; } cv; cv.h = h; return cv.u;
}

// Kernel 1: normalize weight rows -> bf16 packed in ws; zero d_out.
__global__ void wnorm_kernel(const float* __restrict__ w,
                             unsigned int* __restrict__ wn,
                             float* __restrict__ out) {
    const int row = blockIdx.x;      // 128 rows
    const int lane = threadIdx.x;    // 64 lanes
    float2 v = ((const float2*)w)[row * 64 + lane];
    float ss = v.x * v.x + v.y * v.y;
    #pragma unroll
    for (int m = 1; m < 64; m <<= 1) ss += __shfl_xor(ss, m, 64);
    float sc = 1.0f / fmaxf(sqrtf(ss), 1e-12f);
    wn[row * 64 + lane] = bf1(v.x * sc) | (bf1(v.y * sc) << 16);
    if (row == 0 && lane == 0) *out = 0.0f;
}

// Kernel 2: barrier-free fused cosine GEMM + arc-margin + NLL.
// Each wave owns 32 rows end-to-end; B-fragments read straight from L2-hot wn.
__global__ __launch_bounds__(256, 4)
void arcloss_kernel(const float* __restrict__ predict,
                    const float* __restrict__ target,
                    const unsigned short* __restrict__ wns,
                    float* __restrict__ out) {
    __shared__ float swsum[4];
    const int t    = threadIdx.x;
    const int lane = t & 63;
    const int wv   = t >> 6;
    const int l15  = lane & 15;
    const int quad = lane >> 4;
    const long rowbase = (long)blockIdx.x * 128 + wv * 32;  // this wave's 32 rows

    // ---- Labels: lane scans half of row rowbase+(lane&31); one-hot dot with index ----
    int lab_all;
    {
        const int r = lane & 31, half = lane >> 5;
        const float4* trow = (const float4*)(target + (rowbase + r) * NC + half * 64);
        float a0 = 0.f, a1 = 0.f;
        #pragma unroll
        for (int i = 0; i < 16; i += 2) {
            float4 t0 = trow[i];
            float4 t1 = trow[i + 1];
            float c0 = (float)(half * 64 + i * 4);
            a0 = fmaf(t0.x, c0,       a0); a0 = fmaf(t0.y, c0 + 1.f, a0);
            a0 = fmaf(t0.z, c0 + 2.f, a0); a0 = fmaf(t0.w, c0 + 3.f, a0);
            a1 = fmaf(t1.x, c0 + 4.f, a1); a1 = fmaf(t1.y, c0 + 5.f, a1);
            a1 = fmaf(t1.z, c0 + 6.f, a1); a1 = fmaf(t1.w, c0 + 7.f, a1);
        }
        float lf = a0 + a1;
        lf += __shfl_xor(lf, 32, 64);   // combine the two halves of the row
        lab_all = (int)(lf + 0.5f);     // lane L holds label of row (L&31)
    }

    float lsum = 0.0f;

    #pragma unroll 1   // keep rt iterations separate: acc=32 regs, no b-frag CSE across rt
    for (int rt = 0; rt < 2; ++rt) {
        // ---- Predict: load in MFMA A-layout, raw->bf16; row-norm deferred to epilogue ----
        short8 af[4];
        float sc;
        {
            const float* prow = predict + (rowbase + rt * 16 + l15) * NE + quad * 8;
            float s0 = 0.f, s1 = 0.f;
            #pragma unroll
            for (int kc = 0; kc < 4; ++kc) {
                float4 p0 = *(const float4*)(prow + kc * 32);
                float4 p1 = *(const float4*)(prow + kc * 32 + 4);
                s0 += p0.x * p0.x + p0.y * p0.y + p0.z * p0.z + p0.w * p0.w;
                s1 += p1.x * p1.x + p1.y * p1.y + p1.z * p1.z + p1.w * p1.w;
                union { short8 s8; unsigned int u[4]; } uu;
                uu.u[0] = pk2(p0.x, p0.y);
                uu.u[1] = pk2(p0.z, p0.w);
                uu.u[2] = pk2(p1.x, p1.y);
                uu.u[3] = pk2(p1.z, p1.w);
                af[kc] = uu.s8;
            }
            float ss = s0 + s1;
            ss += __shfl_xor(ss, 16, 64);   // lanes {l15,+16,+32,+48} share a row
            ss += __shfl_xor(ss, 32, 64);
            sc = 1.0f / fmaxf(sqrtf(ss), 1e-12f);
        }

        // ---- MFMA: 16 rows x 128 classes, B straight from global (L2-hot, 64B lines) ----
        f32x4 acc[8];
        #pragma unroll
        for (int tc = 0; tc < 8; ++tc) acc[tc] = (f32x4){0.f, 0.f, 0.f, 0.f};
        #pragma unroll 2
        for (int tc = 0; tc < 8; ++tc) {
            short8 b[4];
            #pragma unroll
            for (int kc = 0; kc < 4; ++kc)
                b[kc] = *(const short8*)(wns + (tc * 16 + l15) * 128 + kc * 32 + quad * 8);
            #pragma unroll
            for (int kc = 0; kc < 4; ++kc)
                acc[tc] = __builtin_amdgcn_mfma_f32_16x16x32_bf16(af[kc], b[kc], acc[tc], 0, 0, 0);
        }

        // ---- Epilogue: fixed stabilizer C0; label column EXCLUDED from the sum
        //      (no cancellation: se = sum_{c!=lab} exp + exp(phi-term) > 0 always) ----
        float se[4];
        #pragma unroll
        for (int v = 0; v < 4; ++v) {
            const int rl  = quad * 4 + v;                  // C/D: row = quad*4+reg
            const int lab = __shfl(lab_all, rt * 16 + rl, 64);
            const float scv = __shfl(sc, rl, 64);
            const bool own  = (l15 == (lab & 15));
            const int  tcl  = lab >> 4;
            const float k1  = S_ * scv;                    // exp arg scale
            float s = 1e-38f, craw = 0.f;
            #pragma unroll
            for (int tc = 0; tc < 8; ++tc) {
                float av = acc[tc][v];
                const bool isl = own && (tc == tcl);       // the label column
                s += isl ? 0.f : __expf(fmaf(k1, av, -C0_));
                craw = isl ? av : craw;
            }
            float cl = craw * scv;                         // label cosine (owning lane)
            float s2 = fmaxf(1.0f - cl * cl, 0.0f);
            float ph = cl * COSM_ - sqrtf(s2) * SINM_;
            ph = (cl > TH_) ? ph : (cl - MM_);
            s += own ? __expf(fmaf(S_, ph, -C0_)) : 0.f;   // phi term replaces label col
            lsum -= own ? S_ * ph : 0.f;                   // -L_label, lane-local
            se[v] = s;
        }
        #pragma unroll
        for (int m = 1; m < 16; m <<= 1) {                 // batched: 4 indep shuffles/round
            #pragma unroll
            for (int v = 0; v < 4; ++v) se[v] += __shfl_xor(se[v], m, 64);
        }
        if (l15 == 0) {
            #pragma unroll
            for (int v = 0; v < 4; ++v)
                lsum += __logf(se[v]) + C0_;               // ln(se)+C0
        }
    }

    // ---- Wave + block reduction, one atomic per block ----
    #pragma unroll
    for (int m = 1; m < 64; m <<= 1) lsum += __shfl_xor(lsum, m, 64);
    if (lane == 0) swsum[wv] = lsum;
    __syncthreads();
    if (t == 0) {
        float tot = swsum[0] + swsum[1] + swsum[2] + swsum[3];
        atomicAdd(out, tot * (1.0f / (float)NB));
    }
}

extern "C" void kernel_launch(void* const* d_in, const int* in_sizes, int n_in,
                              void* d_out, int out_size, void* d_ws, size_t ws_size,
                              hipStream_t stream) {
    const float* predict = (const float*)d_in[0];
    const float* target  = (const float*)d_in[1];
    const float* weight  = (const float*)d_in[2];
    float* out = (float*)d_out;
    unsigned int* wn = (unsigned int*)d_ws;  // 128*64 uints = 32 KB bf16 wn

    wnorm_kernel<<<dim3(NC), dim3(64), 0, stream>>>(weight, wn, out);
    arcloss_kernel<<<dim3(NB / 128), dim3(256), 0, stream>>>(predict, target,
                                                             (const unsigned short*)wn, out);
}

// Round 7
// 153.040 us; speedup vs baseline: 1.0992x; 1.0992x over previous
//
#include <hip/hip_runtime.h>
#include <hip/hip_bf16.h>
#include <math.h>

// Problem constants
#define NB 131072
#define NC 128
#define NE 128
__device__ constexpr float S_    = 100.0f;
__device__ constexpr float COSM_ = 0.5403023058681398f;   // cos(1)
__device__ constexpr float SINM_ = 0.8414709848078965f;   // sin(1)
__device__ constexpr float TH_   = -0.5403023058681398f;  // cos(pi-1)
__device__ constexpr float MM_   = 0.8414709848078965f;   // sin(pi-1)*1
__device__ constexpr float C0_   = 25.0f;                 // fixed logsumexp stabilizer

using short8 = __attribute__((ext_vector_type(8))) short;
using f32x4  = __attribute__((ext_vector_type(4))) float;

// fp32 -> bf16 (RNE) on raw bits (kernel 1)
__device__ __forceinline__ unsigned int bf1(float f) {
    unsigned int u = __float_as_uint(f);
    return (u + 0x7FFFu + ((u >> 16) & 1u)) >> 16;
}
// packed fp32x2 -> bf16x2 (v_cvt_pk_bf16_f32)
__device__ __forceinline__ unsigned int pk2(float a, float b) {
    __hip_bfloat162 h = __float22bfloat162_rn(make_float2(a, b));
    union { __hip_bfloat162 h; unsigned int u; } cv; cv.h = h; return cv.u;
}

// Kernel 1: normalize weight rows -> bf16 packed in ws; zero d_out.
__global__ void wnorm_kernel(const float* __restrict__ w,
                             unsigned int* __restrict__ wn,
                             float* __restrict__ out) {
    const int row = blockIdx.x;      // 128 rows
    const int lane = threadIdx.x;    // 64 lanes
    float2 v = ((const float2*)w)[row * 64 + lane];
    float ss = v.x * v.x + v.y * v.y;
    #pragma unroll
    for (int m = 1; m < 64; m <<= 1) ss += __shfl_xor(ss, m, 64);
    float sc = 1.0f / fmaxf(sqrtf(ss), 1e-12f);
    wn[row * 64 + lane] = bf1(v.x * sc) | (bf1(v.y * sc) << 16);
    if (row == 0 && lane == 0) *out = 0.0f;
}

// Kernel 2: fused cosine GEMM + arc-margin + NLL.
// wn staged once into LDS (R3-proven win); rt0 predict + wn loads hoisted for MLP;
// R6-proven lean epilogue (fixed C0, label column excluded from the sum).
__global__ __launch_bounds__(256, 4)
void arcloss_kernel(const float* __restrict__ predict,
                    const float* __restrict__ target,
                    const unsigned short* __restrict__ wns,
                    float* __restrict__ out) {
    constexpr int PITCH = 136;  // ushorts per LDS row (272 B) — breaks pow2 bank stride
    __shared__ __align__(16) unsigned short sw[128 * PITCH];
    __shared__ float swsum[4];

    const int t    = threadIdx.x;
    const int lane = t & 63;
    const int wv   = t >> 6;
    const int l15  = lane & 15;
    const int quad = lane >> 4;
    const long rowbase = (long)blockIdx.x * 128 + wv * 32;  // this wave's 32 rows

    // ---- (1) Issue wn staging loads FIRST (2 threads/row, 8 uint4 each) ----
    const int srow = t >> 1, shalf = t & 1;
    uint4 wbuf[8];
    {
        const uint4* wsrc = (const uint4*)(wns + srow * 128 + shalf * 64);
        #pragma unroll
        for (int j = 0; j < 8; ++j) wbuf[j] = wsrc[j];
    }

    // ---- (2) Issue rt=0 predict loads (8 float4 per lane) ----
    float4 praw0[8];
    {
        const float* prow = predict + (rowbase + l15) * NE + quad * 8;
        #pragma unroll
        for (int kc = 0; kc < 4; ++kc) {
            praw0[kc * 2]     = *(const float4*)(prow + kc * 32);
            praw0[kc * 2 + 1] = *(const float4*)(prow + kc * 32 + 4);
        }
    }

    // ---- (3) Labels: lane scans half of row rowbase+(lane&31), rolling consume ----
    int lab_all;
    {
        const int r = lane & 31, half = lane >> 5;
        const float4* trow = (const float4*)(target + (rowbase + r) * NC + half * 64);
        float a0 = 0.f, a1 = 0.f;
        #pragma unroll
        for (int i = 0; i < 16; i += 2) {
            float4 t0 = trow[i];
            float4 t1 = trow[i + 1];
            float c0 = (float)(half * 64 + i * 4);
            a0 = fmaf(t0.x, c0,       a0); a0 = fmaf(t0.y, c0 + 1.f, a0);
            a0 = fmaf(t0.z, c0 + 2.f, a0); a0 = fmaf(t0.w, c0 + 3.f, a0);
            a1 = fmaf(t1.x, c0 + 4.f, a1); a1 = fmaf(t1.y, c0 + 5.f, a1);
            a1 = fmaf(t1.z, c0 + 6.f, a1); a1 = fmaf(t1.w, c0 + 7.f, a1);
        }
        float lf = a0 + a1;
        lf += __shfl_xor(lf, 32, 64);
        lab_all = (int)(lf + 0.5f);     // lane L holds label of row (L&31)
    }

    // ---- (4) wn -> LDS, single barrier ----
    {
        uint4* dst = (uint4*)(sw + srow * PITCH + shalf * 64);
        #pragma unroll
        for (int j = 0; j < 8; ++j) dst[j] = wbuf[j];
    }
    __syncthreads();

    // ---- rt=0: convert to A-frags + sumsq (norm deferred) ----
    short8 af0[4];
    float sc0;
    {
        float s0 = 0.f;
        #pragma unroll
        for (int kc = 0; kc < 4; ++kc) {
            float4 p0 = praw0[kc * 2], p1 = praw0[kc * 2 + 1];
            s0 += p0.x * p0.x + p0.y * p0.y + p0.z * p0.z + p0.w * p0.w;
            s0 += p1.x * p1.x + p1.y * p1.y + p1.z * p1.z + p1.w * p1.w;
            union { short8 s8; unsigned int u[4]; } uu;
            uu.u[0] = pk2(p0.x, p0.y);
            uu.u[1] = pk2(p0.z, p0.w);
            uu.u[2] = pk2(p1.x, p1.y);
            uu.u[3] = pk2(p1.z, p1.w);
            af0[kc] = uu.s8;
        }
        s0 += __shfl_xor(s0, 16, 64);
        s0 += __shfl_xor(s0, 32, 64);
        sc0 = 1.0f / fmaxf(sqrtf(s0), 1e-12f);
    }

    // ---- Issue rt=1 predict loads now (fly during rt0 MFMA + epilogue) ----
    float4 praw1[8];
    {
        const float* prow = predict + (rowbase + 16 + l15) * NE + quad * 8;
        #pragma unroll
        for (int kc = 0; kc < 4; ++kc) {
            praw1[kc * 2]     = *(const float4*)(prow + kc * 32);
            praw1[kc * 2 + 1] = *(const float4*)(prow + kc * 32 + 4);
        }
    }

    float lsum = 0.0f;

    // ================= rt = 0 =================
    {
        f32x4 acc[8];
        #pragma unroll
        for (int tc = 0; tc < 8; ++tc) acc[tc] = (f32x4){0.f, 0.f, 0.f, 0.f};
        #pragma unroll 2
        for (int tc = 0; tc < 8; ++tc) {
            short8 b[4];
            #pragma unroll
            for (int kc = 0; kc < 4; ++kc)
                b[kc] = *(const short8*)(sw + (tc * 16 + l15) * PITCH + kc * 32 + quad * 8);
            #pragma unroll
            for (int kc = 0; kc < 4; ++kc)
                acc[tc] = __builtin_amdgcn_mfma_f32_16x16x32_bf16(af0[kc], b[kc], acc[tc], 0, 0, 0);
        }
        // epilogue (R6-proven)
        float se[4];
        #pragma unroll
        for (int v = 0; v < 4; ++v) {
            const int rl  = quad * 4 + v;
            const int lab = __shfl(lab_all, rl, 64);
            const float scv = __shfl(sc0, rl, 64);
            const bool own  = (l15 == (lab & 15));
            const int  tcl  = lab >> 4;
            const float k1  = S_ * scv;
            float s = 1e-38f, craw = 0.f;
            #pragma unroll
            for (int tc = 0; tc < 8; ++tc) {
                float av = acc[tc][v];
                const bool isl = own && (tc == tcl);
                s += isl ? 0.f : __expf(fmaf(k1, av, -C0_));
                craw = isl ? av : craw;
            }
            float cl = craw * scv;
            float s2 = fmaxf(1.0f - cl * cl, 0.0f);
            float ph = cl * COSM_ - sqrtf(s2) * SINM_;
            ph = (cl > TH_) ? ph : (cl - MM_);
            s += own ? __expf(fmaf(S_, ph, -C0_)) : 0.f;
            lsum -= own ? S_ * ph : 0.f;
            se[v] = s;
        }
        #pragma unroll
        for (int m = 1; m < 16; m <<= 1) {
            #pragma unroll
            for (int v = 0; v < 4; ++v) se[v] += __shfl_xor(se[v], m, 64);
        }
        if (l15 == 0) {
            #pragma unroll
            for (int v = 0; v < 4; ++v) lsum += __logf(se[v]) + C0_;
        }
    }

    // ================= rt = 1 =================
    {
        short8 af1[4];
        float sc1;
        {
            float s0 = 0.f;
            #pragma unroll
            for (int kc = 0; kc < 4; ++kc) {
                float4 p0 = praw1[kc * 2], p1 = praw1[kc * 2 + 1];
                s0 += p0.x * p0.x + p0.y * p0.y + p0.z * p0.z + p0.w * p0.w;
                s0 += p1.x * p1.x + p1.y * p1.y + p1.z * p1.z + p1.w * p1.w;
                union { short8 s8; unsigned int u[4]; } uu;
                uu.u[0] = pk2(p0.x, p0.y);
                uu.u[1] = pk2(p0.z, p0.w);
                uu.u[2] = pk2(p1.x, p1.y);
                uu.u[3] = pk2(p1.z, p1.w);
                af1[kc] = uu.s8;
            }
            s0 += __shfl_xor(s0, 16, 64);
            s0 += __shfl_xor(s0, 32, 64);
            sc1 = 1.0f / fmaxf(sqrtf(s0), 1e-12f);
        }
        f32x4 acc[8];
        #pragma unroll
        for (int tc = 0; tc < 8; ++tc) acc[tc] = (f32x4){0.f, 0.f, 0.f, 0.f};
        #pragma unroll 2
        for (int tc = 0; tc < 8; ++tc) {
            short8 b[4];
            #pragma unroll
            for (int kc = 0; kc < 4; ++kc)
                b[kc] = *(const short8*)(sw + (tc * 16 + l15) * PITCH + kc * 32 + quad * 8);
            #pragma unroll
            for (int kc = 0; kc < 4; ++kc)
                acc[tc] = __builtin_amdgcn_mfma_f32_16x16x32_bf16(af1[kc], b[kc], acc[tc], 0, 0, 0);
        }
        float se[4];
        #pragma unroll
        for (int v = 0; v < 4; ++v) {
            const int rl  = quad * 4 + v;
            const int lab = __shfl(lab_all, 16 + rl, 64);
            const float scv = __shfl(sc1, rl, 64);
            const bool own  = (l15 == (lab & 15));
            const int  tcl  = lab >> 4;
            const float k1  = S_ * scv;
            float s = 1e-38f, craw = 0.f;
            #pragma unroll
            for (int tc = 0; tc < 8; ++tc) {
                float av = acc[tc][v];
                const bool isl = own && (tc == tcl);
                s += isl ? 0.f : __expf(fmaf(k1, av, -C0_));
                craw = isl ? av : craw;
            }
            float cl = craw * scv;
            float s2 = fmaxf(1.0f - cl * cl, 0.0f);
            float ph = cl * COSM_ - sqrtf(s2) * SINM_;
            ph = (cl > TH_) ? ph : (cl - MM_);
            s += own ? __expf(fmaf(S_, ph, -C0_)) : 0.f;
            lsum -= own ? S_ * ph : 0.f;
            se[v] = s;
        }
        #pragma unroll
        for (int m = 1; m < 16; m <<= 1) {
            #pragma unroll
            for (int v = 0; v < 4; ++v) se[v] += __shfl_xor(se[v], m, 64);
        }
        if (l15 == 0) {
            #pragma unroll
            for (int v = 0; v < 4; ++v) lsum += __logf(se[v]) + C0_;
        }
    }

    // ---- Wave + block reduction, one atomic per block ----
    #pragma unroll
    for (int m = 1; m < 64; m <<= 1) lsum += __shfl_xor(lsum, m, 64);
    if (lane == 0) swsum[wv] = lsum;
    __syncthreads();
    if (t == 0) {
        float tot = swsum[0] + swsum[1] + swsum[2] + swsum[3];
        atomicAdd(out, tot * (1.0f / (float)NB));
    }
}

extern "C" void kernel_launch(void* const* d_in, const int* in_sizes, int n_in,
                              void* d_out, int out_size, void* d_ws, size_t ws_size,
                              hipStream_t stream) {
    const float* predict = (const float*)d_in[0];
    const float* target  = (const float*)d_in[1];
    const float* weight  = (const float*)d_in[2];
    float* out = (float*)d_out;
    unsigned int* wn = (unsigned int*)d_ws;  // 128*64 uints = 32 KB bf16 wn

    wnorm_kernel<<<dim3(NC), dim3(64), 0, stream>>>(weight, wn, out);
    arcloss_kernel<<<dim3(NB / 128), dim3(256), 0, stream>>>(predict, target,
                                                             (const unsigned short*)wn, out);
}